// Round 4
// baseline (148.082 us; speedup 1.0000x reference)
//
#include <hip/hip_runtime.h>
#include <stdint.h>

#define D 128
#define B_ROWS 8192
#define NT 64                        // number of 128-row tiles
#define NPAIRBLK (NT * (NT + 1) / 2) // 2080 upper-triangle tile blocks
#define NBLK 256                     // one block per CU: co-residency by pigeonhole
#define LW 136                       // mlp act row stride in halfwords (128+8 pad)
#define SPIN_CAP (1 << 20)           // no-hang safety bail (~100ms worst case)

typedef __bf16 bf16x8 __attribute__((ext_vector_type(8)));
typedef float f32x4 __attribute__((ext_vector_type(4)));

// Single ordinary kernel: MLP -> software grid barrier (flag array, poison-
// immune since 0xAAAAAAAA != 1) -> pairwise loss -> block-0 final reduce.
// 256 blocks x 256 threads; all blocks co-resident (1 block always fits a CU).
__global__ __launch_bounds__(256) void fused_kernel(
    const float* __restrict__ X,
    const float* __restrict__ W1, const float* __restrict__ b1,
    const float* __restrict__ W2, const float* __restrict__ b2,
    const float* __restrict__ W3, const float* __restrict__ b3,
    const int* __restrict__ y,
    unsigned short* __restrict__ hb, float* __restrict__ sq,
    float* __restrict__ wsPairP, float* __restrict__ wsSqP,
    unsigned int* __restrict__ flag1, unsigned int* __restrict__ flag2,
    float* __restrict__ out)
{
    __shared__ unsigned short ldsA[128 * 128]; // 32KB (aliases MLP act bufs)
    __shared__ unsigned short ldsB[128 * 128]; // 32KB
    __shared__ float sA[128], sB[128];
    __shared__ int yA[128], yB[128];
    __shared__ float red[4], red2[4];

    const int t = threadIdx.x;
    const int lane = t & 63;
    const int w = t >> 6;
    const int bid = blockIdx.x;

    // ================= Phase 1: MLP, 32 rows/block in two 16-row halves ======
    float sqAcc = 0.f; // meaningful at t==0
    {
        unsigned short* actA = ldsA;            // 16*LW hw
        unsigned short* actB = ldsA + 16 * LW;
        const int ll = lane & 15;
        const int q  = lane >> 4;
        const int nb0 = w * 32;

        auto layer = [&](const unsigned short* __restrict__ actIn,
                         unsigned short* __restrict__ actOut,
                         const float* __restrict__ Wg,
                         const float* __restrict__ bg, bool do_relu) {
            f32x4 acc0 = {0.f, 0.f, 0.f, 0.f};
            f32x4 acc1 = {0.f, 0.f, 0.f, 0.f};
            #pragma unroll
            for (int kk = 0; kk < 4; ++kk) {
                bf16x8 a = *(const bf16x8*)(actIn + ll * LW + kk * 32 + q * 8);
                float wv0[8], wv1[8];
                #pragma unroll
                for (int j = 0; j < 8; ++j) {
                    const int kg = kk * 32 + q * 8 + j;
                    wv0[j] = Wg[kg * D + nb0 + ll];
                    wv1[j] = Wg[kg * D + nb0 + 16 + ll];
                }
                bf16x8 b0v, b1v;
                #pragma unroll
                for (int j = 0; j < 8; ++j) {
                    b0v[j] = (__bf16)wv0[j];
                    b1v[j] = (__bf16)wv1[j];
                }
                acc0 = __builtin_amdgcn_mfma_f32_16x16x32_bf16(a, b0v, acc0, 0, 0, 0);
                acc1 = __builtin_amdgcn_mfma_f32_16x16x32_bf16(a, b1v, acc1, 0, 0, 0);
            }
            const float bb0 = bg[nb0 + ll];
            const float bb1 = bg[nb0 + 16 + ll];
            #pragma unroll
            for (int rr = 0; rr < 4; ++rr) {
                const int m = q * 4 + rr;
                float v0 = acc0[rr] + bb0;
                float v1 = acc1[rr] + bb1;
                if (do_relu) { v0 = fmaxf(v0, 0.f); v1 = fmaxf(v1, 0.f); }
                *(__bf16*)(actOut + m * LW + nb0 + ll)      = (__bf16)v0;
                *(__bf16*)(actOut + m * LW + nb0 + 16 + ll) = (__bf16)v1;
            }
        };

        for (int half = 0; half < 2; ++half) {
            const int row0 = bid * 32 + half * 16;

            // stage X -> actA as bf16
            {
                const int r  = t >> 4;         // 0..15
                const int c8 = (t & 15) * 8;   // k chunk of 8
                const float* xp = X + (size_t)(row0 + r) * D + c8;
                float4 v0 = *(const float4*)(xp);
                float4 v1 = *(const float4*)(xp + 4);
                bf16x8 u;
                u[0] = (__bf16)v0.x; u[1] = (__bf16)v0.y; u[2] = (__bf16)v0.z; u[3] = (__bf16)v0.w;
                u[4] = (__bf16)v1.x; u[5] = (__bf16)v1.y; u[6] = (__bf16)v1.z; u[7] = (__bf16)v1.w;
                *(bf16x8*)(actA + r * LW + c8) = u;
            }
            __syncthreads();

            layer(actA, actB, W1, b1, true);
            __syncthreads();
            layer(actB, actA, W2, b2, true);
            __syncthreads();
            layer(actA, actB, W3, b3, false);
            __syncthreads();

            // epilogue: write hb (agent-scope stores), per-row sq, block partial
            {
                const int r  = t >> 4;
                const int c8 = (t & 15) * 8;
                bf16x8 hv = *(const bf16x8*)(actB + r * LW + c8);
                union { bf16x8 v; uint64_t u[2]; } cv; cv.v = hv;
                uint64_t* hp = (uint64_t*)(hb + (size_t)(row0 + r) * D + c8);
                __hip_atomic_store(hp,     cv.u[0], __ATOMIC_RELAXED, __HIP_MEMORY_SCOPE_AGENT);
                __hip_atomic_store(hp + 1, cv.u[1], __ATOMIC_RELAXED, __HIP_MEMORY_SCOPE_AGENT);
                float ps = 0.f;
                #pragma unroll
                for (int j = 0; j < 8; ++j) {
                    float f = (float)hv[j];
                    ps = fmaf(f, f, ps);
                }
                #pragma unroll
                for (int m = 1; m < 16; m <<= 1) ps += __shfl_xor(ps, m, 64);
                if ((t & 15) == 0)
                    __hip_atomic_store(&sq[row0 + r], ps, __ATOMIC_RELAXED, __HIP_MEMORY_SCOPE_AGENT);
                ps += __shfl_xor(ps, 16, 64);
                ps += __shfl_xor(ps, 32, 64);
                if (lane == 0) red[w] = ps;
                __syncthreads();
                if (t == 0) sqAcc += red[0] + red[1] + red[2] + red[3];
            }
        }
    }

    // publish phase-1 results + arrive at grid barrier
    if (t == 0) {
        __hip_atomic_store(&wsSqP[bid], sqAcc, __ATOMIC_RELAXED, __HIP_MEMORY_SCOPE_AGENT);
        __threadfence();
        __hip_atomic_store(&flag1[bid], 1u, __ATOMIC_RELEASE, __HIP_MEMORY_SCOPE_AGENT);
    }
    // grid barrier: thread t waits for block t (256 threads <-> 256 blocks)
    {
        int it = 0;
        while (__hip_atomic_load(&flag1[t], __ATOMIC_ACQUIRE, __HIP_MEMORY_SCOPE_AGENT) != 1u
               && it < SPIN_CAP) { __builtin_amdgcn_s_sleep(2); ++it; }
        __threadfence();
        __syncthreads();
    }

    // ================= Phase 2: pairwise tiles (ti-major, A-tile reuse) ======
    float s_acc = 0.f;
    {
        const int wr = w >> 1, wc = w & 1;
        const int lh = lane >> 4;
        const int ll = lane & 15;

        const int Tstart = (NPAIRBLK * bid) / NBLK;
        const int Tend   = (NPAIRBLK * (bid + 1)) / NBLK;

        auto stage_tile = [&](const unsigned short* __restrict__ srcbase,
                              unsigned short* __restrict__ lds) {
            #pragma unroll
            for (int it = 0; it < 8; ++it) {
                const int fbase = w * 512 + it * 64; // wave-uniform chunk base
                const int f = fbase + lane;
                const int r = f >> 4;
                const int c = f & 15;
                const int gc = c ^ (r & 15);         // XOR swizzle
                const unsigned short* src = srcbase + (size_t)r * D + gc * 8;
                unsigned short* dst = lds + (size_t)fbase * 8;
                __builtin_amdgcn_global_load_lds(
                    (const __attribute__((address_space(1))) void*)src,
                    (__attribute__((address_space(3))) void*)dst, 16, 0, 0);
            }
        };

        int ti = 0, rem = Tstart;
        while (rem >= NT - ti) { rem -= NT - ti; ++ti; }
        int tj = ti + rem;
        int prev_ti = -1;

        for (int T = Tstart; T < Tend; ++T) {
            const int i0 = ti * 128, j0 = tj * 128;
            __syncthreads(); // previous tile's LDS reads done before overwrite

            const bool newA = (ti != prev_ti);
            if (t < 128) { sB[t] = sq[j0 + t]; yB[t] = y[j0 + t]; }
            else if (newA) { int u = t - 128; sA[u] = sq[i0 + u]; yA[u] = y[i0 + u]; }
            if (newA) stage_tile(hb + (size_t)i0 * D, ldsA);
            stage_tile(hb + (size_t)j0 * D, ldsB);
            prev_ti = ti;
            __syncthreads();

            f32x4 acc[4][4];
            const f32x4 z4 = {0.f, 0.f, 0.f, 0.f};
            #pragma unroll
            for (int a = 0; a < 4; ++a)
                #pragma unroll
                for (int c = 0; c < 4; ++c) acc[a][c] = z4;

            #pragma unroll
            for (int kk = 0; kk < 4; ++kk) {
                bf16x8 af[4], bfr[4];
                const int clog = kk * 4 + lh;
                const int phys = clog ^ ll;
                #pragma unroll
                for (int tr = 0; tr < 4; ++tr) {
                    const int rowl = wr * 64 + tr * 16 + ll;
                    af[tr] = *(const bf16x8*)(ldsA + rowl * 128 + phys * 8);
                }
                #pragma unroll
                for (int tc = 0; tc < 4; ++tc) {
                    const int rowl = wc * 64 + tc * 16 + ll;
                    bfr[tc] = *(const bf16x8*)(ldsB + rowl * 128 + phys * 8);
                }
                #pragma unroll
                for (int tr = 0; tr < 4; ++tr)
                    #pragma unroll
                    for (int tc = 0; tc < 4; ++tc)
                        acc[tr][tc] = __builtin_amdgcn_mfma_f32_16x16x32_bf16(
                            af[tr], bfr[tc], acc[tr][tc], 0, 0, 0);
            }

            float si[16]; int yi[16];
            #pragma unroll
            for (int tr = 0; tr < 4; ++tr)
                #pragma unroll
                for (int rr = 0; rr < 4; ++rr) {
                    const int iloc = wr * 64 + tr * 16 + lh * 4 + rr;
                    si[tr * 4 + rr] = sA[iloc];
                    yi[tr * 4 + rr] = yA[iloc];
                }
            float sj[4]; int yj[4];
            #pragma unroll
            for (int tc = 0; tc < 4; ++tc) {
                const int jloc = wc * 64 + tc * 16 + ll;
                sj[tc] = sB[jloc]; yj[tc] = yB[jloc];
            }

            // -log(1.01 - e) ~= -log(1.01) + e/1.01 + e^2/(2*1.01^2)
            float s = 0.f;
            #pragma unroll
            for (int tr = 0; tr < 4; ++tr)
                #pragma unroll
                for (int rr = 0; rr < 4; ++rr) {
                    const float sii = si[tr * 4 + rr];
                    const int   yii = yi[tr * 4 + rr];
                    #pragma unroll
                    for (int tc = 0; tc < 4; ++tc) {
                        const float dot = acc[tr][tc][rr];
                        float d = fmaxf(fmaf(-2.f, dot, sii + sj[tc]), 0.f);
                        float e = __builtin_amdgcn_exp2f(d * -1.442695041f);
                        float nlg = fmaf(e, fmaf(e, 0.49014802f, 0.99009901f), -0.00995033f);
                        s += (yii != yj[tc]) ? nlg : d;
                    }
                }

            const float wgt = (ti == tj) ? 1.f : 2.f;
            s_acc = fmaf(wgt, s, s_acc);

            if (++tj >= NT) { ++ti; tj = ti; }
        }
    }

    // block reduce + publish phase-2 partial
    #pragma unroll
    for (int m = 1; m < 64; m <<= 1) s_acc += __shfl_xor(s_acc, m, 64);
    __syncthreads();
    if (lane == 0) red[w] = s_acc;
    __syncthreads();
    if (t == 0) {
        const float A = red[0] + red[1] + red[2] + red[3];
        __hip_atomic_store(&wsPairP[bid], A, __ATOMIC_RELAXED, __HIP_MEMORY_SCOPE_AGENT);
        __threadfence();
        __hip_atomic_store(&flag2[bid], 1u, __ATOMIC_RELEASE, __HIP_MEMORY_SCOPE_AGENT);
    }

    // ================= Phase 3: block 0 waits for all, reduces ===============
    if (bid == 0) {
        int it = 0;
        while (__hip_atomic_load(&flag2[t], __ATOMIC_ACQUIRE, __HIP_MEMORY_SCOPE_AGENT) != 1u
               && it < SPIN_CAP) { __builtin_amdgcn_s_sleep(2); ++it; }
        __threadfence();
        __syncthreads();

        float a1 = __hip_atomic_load(&wsPairP[t], __ATOMIC_RELAXED, __HIP_MEMORY_SCOPE_AGENT);
        float a3 = __hip_atomic_load(&wsSqP[t],  __ATOMIC_RELAXED, __HIP_MEMORY_SCOPE_AGENT);
        #pragma unroll
        for (int m = 1; m < 64; m <<= 1) {
            a1 += __shfl_xor(a1, m, 64);
            a3 += __shfl_xor(a3, m, 64);
        }
        if (lane == 0) { red[w] = a1; red2[w] = a3; }
        __syncthreads();
        if (t == 0) {
            const float A1 = red[0] + red[1] + red[2] + red[3];
            const float A3 = red2[0] + red2[1] + red2[2] + red2[3];
            const float invB2 = 1.0f / (8192.0f * 8192.0f); // exact: 2^-26
            out[0] = A1 * invB2 + 0.01f * A3 / (8192.0f * 128.0f);
        }
    }
}

extern "C" void kernel_launch(void* const* d_in, const int* in_sizes, int n_in,
                              void* d_out, int out_size, void* d_ws, size_t ws_size,
                              hipStream_t stream) {
    (void)in_sizes; (void)n_in; (void)out_size; (void)ws_size;
    const float* X  = (const float*)d_in[0];
    const float* W1 = (const float*)d_in[1];
    const float* b1 = (const float*)d_in[2];
    const float* W2 = (const float*)d_in[3];
    const float* b2 = (const float*)d_in[4];
    const float* W3 = (const float*)d_in[5];
    const float* b3 = (const float*)d_in[6];
    const int*   y  = (const int*)d_in[7];

    char* ws = (char*)d_ws;
    unsigned short* hb = (unsigned short*)ws;                        // 2 MB
    char* p = ws + (size_t)B_ROWS * D * 2;
    float* sq = (float*)p;                 p += (size_t)B_ROWS * 4;  // 32 KB
    float* wsPairP = (float*)p;            p += NBLK * 4;
    float* wsSqP = (float*)p;              p += NBLK * 4;
    unsigned int* flag1 = (unsigned int*)p; p += NBLK * 4;
    unsigned int* flag2 = (unsigned int*)p;

    fused_kernel<<<NBLK, 256, 0, stream>>>(X, W1, b1, W2, b2, W3, b3, y,
                                           hb, sq, wsPairP, wsSqP,
                                           flag1, flag2, (float*)d_out);
}

// Round 5
// 127.881 us; speedup vs baseline: 1.1580x; 1.1580x over previous
//
#include <hip/hip_runtime.h>
#include <stdint.h>

#define D 128
#define B_ROWS 8192
#define NT 64                        // number of 128-row tiles
#define NPAIRBLK (NT * (NT + 1) / 2) // 2080 upper-triangle tile blocks
#define NMLPBLK 512
#define LW 136                       // mlp act row stride in halfwords (128+8 pad)

typedef __bf16 bf16x8 __attribute__((ext_vector_type(8)));
typedef float f32x4 __attribute__((ext_vector_type(4)));

// ---------------- MLP: h = relu(relu(X@W1+b1)@W2+b2)@W3+b3 ------------------
// 512 blocks x 16 rows, 256 threads (4 waves), 2 blocks/CU. bf16 MFMA.
// Also: block 0 zeroes the pair-kernel's counter/accum cells (poison-immune
// handoff; kernel boundary on the stream publishes them), and each block
// stores its sum(h^2) partial to wsSqP.
__global__ __launch_bounds__(256, 2) void mlp_kernel(
    const float* __restrict__ X,
    const float* __restrict__ W1, const float* __restrict__ b1,
    const float* __restrict__ W2, const float* __restrict__ b2,
    const float* __restrict__ W3, const float* __restrict__ b3,
    unsigned short* __restrict__ hb, float* __restrict__ sq,
    float* __restrict__ wsSqP, unsigned int* __restrict__ counter,
    float* __restrict__ accum)
{
    __shared__ unsigned short actA[16 * LW];
    __shared__ unsigned short actB[16 * LW];
    __shared__ float red[4];

    const int t = threadIdx.x;
    const int lane = t & 63;
    const int w = t >> 6;
    const int row0 = blockIdx.x * 16;
    const int ll = lane & 15;
    const int q  = lane >> 4;
    const int nb0 = w * 32;

    if (blockIdx.x == 0 && t == 0) {
        __hip_atomic_store(counter, 0u, __ATOMIC_RELAXED, __HIP_MEMORY_SCOPE_AGENT);
        __hip_atomic_store(accum, 0.f, __ATOMIC_RELAXED, __HIP_MEMORY_SCOPE_AGENT);
    }

    // stage X -> actA as bf16
    {
        const int r  = t >> 4;         // 0..15
        const int c8 = (t & 15) * 8;   // k chunk of 8
        const float* xp = X + (size_t)(row0 + r) * D + c8;
        float4 v0 = *(const float4*)(xp);
        float4 v1 = *(const float4*)(xp + 4);
        bf16x8 u;
        u[0] = (__bf16)v0.x; u[1] = (__bf16)v0.y; u[2] = (__bf16)v0.z; u[3] = (__bf16)v0.w;
        u[4] = (__bf16)v1.x; u[5] = (__bf16)v1.y; u[6] = (__bf16)v1.z; u[7] = (__bf16)v1.w;
        *(bf16x8*)(actA + r * LW + c8) = u;
    }
    __syncthreads();

    auto layer = [&](const unsigned short* __restrict__ actIn,
                     unsigned short* __restrict__ actOut,
                     const float* __restrict__ Wg,
                     const float* __restrict__ bg, bool do_relu) {
        f32x4 acc0 = {0.f, 0.f, 0.f, 0.f};
        f32x4 acc1 = {0.f, 0.f, 0.f, 0.f};
        #pragma unroll
        for (int kk = 0; kk < 4; ++kk) {
            bf16x8 a = *(const bf16x8*)(actIn + ll * LW + kk * 32 + q * 8);
            float wv0[8], wv1[8];
            #pragma unroll
            for (int j = 0; j < 8; ++j) {
                const int kg = kk * 32 + q * 8 + j;
                wv0[j] = Wg[kg * D + nb0 + ll];
                wv1[j] = Wg[kg * D + nb0 + 16 + ll];
            }
            bf16x8 b0v, b1v;
            #pragma unroll
            for (int j = 0; j < 8; ++j) {
                b0v[j] = (__bf16)wv0[j];
                b1v[j] = (__bf16)wv1[j];
            }
            acc0 = __builtin_amdgcn_mfma_f32_16x16x32_bf16(a, b0v, acc0, 0, 0, 0);
            acc1 = __builtin_amdgcn_mfma_f32_16x16x32_bf16(a, b1v, acc1, 0, 0, 0);
        }
        const float bb0 = bg[nb0 + ll];
        const float bb1 = bg[nb0 + 16 + ll];
        #pragma unroll
        for (int rr = 0; rr < 4; ++rr) {
            const int m = q * 4 + rr;
            float v0 = acc0[rr] + bb0;
            float v1 = acc1[rr] + bb1;
            if (do_relu) { v0 = fmaxf(v0, 0.f); v1 = fmaxf(v1, 0.f); }
            *(__bf16*)(actOut + m * LW + nb0 + ll)      = (__bf16)v0;
            *(__bf16*)(actOut + m * LW + nb0 + 16 + ll) = (__bf16)v1;
        }
    };

    layer(actA, actB, W1, b1, true);
    __syncthreads();
    layer(actB, actA, W2, b2, true);
    __syncthreads();
    layer(actA, actB, W3, b3, false);
    __syncthreads();

    // epilogue: write hb (bf16), per-row sq, block partial -> wsSqP
    {
        const int r  = t >> 4;
        const int c8 = (t & 15) * 8;
        bf16x8 hv = *(const bf16x8*)(actB + r * LW + c8);
        *(bf16x8*)(hb + (size_t)(row0 + r) * D + c8) = hv;
        float ps = 0.f;
        #pragma unroll
        for (int j = 0; j < 8; ++j) {
            float f = (float)hv[j];
            ps = fmaf(f, f, ps);
        }
        #pragma unroll
        for (int m = 1; m < 16; m <<= 1) ps += __shfl_xor(ps, m, 64);
        if ((t & 15) == 0) sq[row0 + r] = ps;
        ps += __shfl_xor(ps, 16, 64);
        ps += __shfl_xor(ps, 32, 64);
        if (lane == 0) red[w] = ps;
        __syncthreads();
        if (t == 0) wsSqP[blockIdx.x] = red[0] + red[1] + red[2] + red[3];
    }
}

// ---------------- Pairwise fused dist+loss over 128x128 tiles ----------------
// 2080 blocks x 512 threads (8 waves in 4x2), 2 blocks/CU -> 16 waves/CU.
// Upper-triangle tile (ti<=tj); off-diag weighted x2. Last-finishing block
// (device-scope counter) folds in sum(sq) and writes the scalar out.
__global__ __launch_bounds__(512, 4) void pair_kernel(
    const unsigned short* __restrict__ hb, const float* __restrict__ sq,
    const int* __restrict__ y, const float* __restrict__ wsSqP,
    unsigned int* __restrict__ counter, float* __restrict__ accum,
    float* __restrict__ out)
{
    __shared__ unsigned short ldsA[128 * 128]; // 32KB, swizzled
    __shared__ unsigned short ldsB[128 * 128];
    __shared__ float sA[128], sB[128];
    __shared__ int yA[128], yB[128];
    __shared__ float red[8];
    __shared__ int isLast;

    const int t = threadIdx.x;
    const int lane = t & 63;
    const int w = t >> 6;       // 0..7

    int b = blockIdx.x, ti = 0;
    while (b >= NT - ti) { b -= NT - ti; ++ti; }
    const int tj = ti + b;
    const int i0 = ti * 128, j0 = tj * 128;

    if (t < 128) { sA[t] = sq[i0 + t]; yA[t] = y[i0 + t]; }
    else if (t < 256) { int u = t - 128; sB[u] = sq[j0 + u]; yB[u] = y[j0 + u]; }

    // stage both tiles: 4096 chunks of 16B; wave w covers chunks [w*512, +512)
    #pragma unroll
    for (int it = 0; it < 8; ++it) {
        const int fbase = w * 512 + it * 64;  // wave-uniform
        const int f = fbase + lane;
        const int tile = fbase >> 11;         // wave-uniform (0=A,1=B)
        const int r = (f >> 4) & 127;
        const int c = f & 15;
        const int gc = c ^ (r & 15);          // XOR swizzle
        const unsigned short* src =
            hb + (size_t)((tile ? j0 : i0) + r) * D + gc * 8;
        unsigned short* dstbase =
            (tile ? ldsB : ldsA) + (size_t)(fbase & 2047) * 8;
        __builtin_amdgcn_global_load_lds(
            (const __attribute__((address_space(1))) void*)src,
            (__attribute__((address_space(3))) void*)dstbase, 16, 0, 0);
    }
    __syncthreads();

    // wave grid: wr in 0..3 (32 rows each), wc in 0..1 (64 cols each)
    const int wr = w >> 1, wc = w & 1;
    const int lh = lane >> 4;   // quad 0..3
    const int ll = lane & 15;

    f32x4 acc[2][4];
    const f32x4 z4 = {0.f, 0.f, 0.f, 0.f};
    #pragma unroll
    for (int a = 0; a < 2; ++a)
        #pragma unroll
        for (int c = 0; c < 4; ++c) acc[a][c] = z4;

    #pragma unroll
    for (int kk = 0; kk < 4; ++kk) {
        bf16x8 af[2], bfr[4];
        const int clog = kk * 4 + lh;
        const int phys = clog ^ ll; // (row&15)==ll for all our rows
        #pragma unroll
        for (int tr = 0; tr < 2; ++tr) {
            const int rowl = wr * 32 + tr * 16 + ll;
            af[tr] = *(const bf16x8*)(ldsA + rowl * 128 + phys * 8);
        }
        #pragma unroll
        for (int tc = 0; tc < 4; ++tc) {
            const int rowl = wc * 64 + tc * 16 + ll;
            bfr[tc] = *(const bf16x8*)(ldsB + rowl * 128 + phys * 8);
        }
        #pragma unroll
        for (int tr = 0; tr < 2; ++tr)
            #pragma unroll
            for (int tc = 0; tc < 4; ++tc)
                acc[tr][tc] = __builtin_amdgcn_mfma_f32_16x16x32_bf16(
                    af[tr], bfr[tc], acc[tr][tc], 0, 0, 0);
    }

    // epilogue: d = max(si + sj - 2*dot, 0); contrib = neq ? -log(1.01-e^-d) : d
    float si[8]; int yi[8];
    #pragma unroll
    for (int tr = 0; tr < 2; ++tr)
        #pragma unroll
        for (int rr = 0; rr < 4; ++rr) {
            const int iloc = wr * 32 + tr * 16 + lh * 4 + rr;
            si[tr * 4 + rr] = sA[iloc];
            yi[tr * 4 + rr] = yA[iloc];
        }
    float sj[4]; int yj[4];
    #pragma unroll
    for (int tc = 0; tc < 4; ++tc) {
        const int jloc = wc * 64 + tc * 16 + ll;
        sj[tc] = sB[jloc]; yj[tc] = yB[jloc];
    }

    // -log(1.01 - e) ~= -log(1.01) + e/1.01 + e^2/(2*1.01^2)
    float s = 0.f;
    #pragma unroll
    for (int tr = 0; tr < 2; ++tr)
        #pragma unroll
        for (int rr = 0; rr < 4; ++rr) {
            const float sii = si[tr * 4 + rr];
            const int   yii = yi[tr * 4 + rr];
            #pragma unroll
            for (int tc = 0; tc < 4; ++tc) {
                const float dot = acc[tr][tc][rr];
                float d = fmaxf(fmaf(-2.f, dot, sii + sj[tc]), 0.f);
                float e = __builtin_amdgcn_exp2f(d * -1.442695041f);
                float nlg = fmaf(e, fmaf(e, 0.49014802f, 0.99009901f), -0.00995033f);
                s += (yii != yj[tc]) ? nlg : d;
            }
        }

    #pragma unroll
    for (int m = 1; m < 64; m <<= 1) s += __shfl_xor(s, m, 64);
    if (lane == 0) red[w] = s;
    __syncthreads();
    if (t == 0) {
        const float wgt = (ti == tj) ? 1.f : 2.f;
        float A = wgt * (red[0] + red[1] + red[2] + red[3] +
                         red[4] + red[5] + red[6] + red[7]);
        atomicAdd(accum, A);          // device-scope by default (m20)
        __threadfence();
        unsigned int old = atomicAdd(counter, 1u);
        isLast = (old == NPAIRBLK - 1) ? 1 : 0;
    }
    __syncthreads();

    if (isLast) {
        __threadfence();
        // 512 threads <-> 512 mlp partials, exactly
        float a3 = wsSqP[t];
        #pragma unroll
        for (int m = 1; m < 64; m <<= 1) a3 += __shfl_xor(a3, m, 64);
        if (lane == 0) red[w] = a3;
        __syncthreads();
        if (t == 0) {
            const float A3 = red[0] + red[1] + red[2] + red[3] +
                             red[4] + red[5] + red[6] + red[7];
            const float A1 = __hip_atomic_load(accum, __ATOMIC_RELAXED,
                                               __HIP_MEMORY_SCOPE_AGENT);
            const float invB2 = 1.0f / (8192.0f * 8192.0f); // exact: 2^-26
            out[0] = A1 * invB2 + 0.01f * A3 / (8192.0f * 128.0f);
        }
    }
}

extern "C" void kernel_launch(void* const* d_in, const int* in_sizes, int n_in,
                              void* d_out, int out_size, void* d_ws, size_t ws_size,
                              hipStream_t stream) {
    (void)in_sizes; (void)n_in; (void)out_size; (void)ws_size;
    const float* X  = (const float*)d_in[0];
    const float* W1 = (const float*)d_in[1];
    const float* b1 = (const float*)d_in[2];
    const float* W2 = (const float*)d_in[3];
    const float* b2 = (const float*)d_in[4];
    const float* W3 = (const float*)d_in[5];
    const float* b3 = (const float*)d_in[6];
    const int*   y  = (const int*)d_in[7];

    char* ws = (char*)d_ws;
    unsigned short* hb = (unsigned short*)ws;                        // 2 MB
    char* p = ws + (size_t)B_ROWS * D * 2;
    float* sq = (float*)p;                  p += (size_t)B_ROWS * 4; // 32 KB
    float* wsSqP = (float*)p;               p += NMLPBLK * 4;
    unsigned int* counter = (unsigned int*)p; p += 64;               // pad cacheline
    float* accum = (float*)p;

    mlp_kernel<<<NMLPBLK, 256, 0, stream>>>(X, W1, b1, W2, b2, W3, b3,
                                            hb, sq, wsSqP, counter, accum);
    pair_kernel<<<NPAIRBLK, 512, 0, stream>>>(hb, sq, y, wsSqP,
                                              counter, accum, (float*)d_out);
}